// Round 11
// baseline (449.610 us; speedup 1.0000x reference)
//
#include <hip/hip_runtime.h>
#include <math.h>

#define BATCH 128
#define SEQ 512
#define DIN 16
#define HID 32
#define G4 128   // 4*HID
#define DH 64    // 2*HID
#define LOG2E 1.44269504f

__device__ __forceinline__ float rcpf(float x) { return __builtin_amdgcn_rcpf(x); }
__device__ __forceinline__ float sigf(float x) { return rcpf(1.0f + exp2f(x * -LOG2E)); }
__device__ __forceinline__ float tanh_fast(float x) {
    return 1.0f - 2.0f * rcpf(1.0f + exp2f(x * (2.0f * LOG2E)));
}
__device__ __forceinline__ float rlane(float v, int lane) {
    return __int_as_float(__builtin_amdgcn_readlane(__float_as_int(v), lane));
}

// ---------------- Kernel 0: xW precompute ----------------
// xw[b][dir][t][col] = bias[col] + sum_d x[b][t][d] * W[d][col]
__global__ __launch_bounds__(256) void xw_kernel(
    const float* __restrict__ x,
    const float* __restrict__ Wf, const float* __restrict__ bf,
    const float* __restrict__ Wb, const float* __restrict__ bb,
    float* __restrict__ xw)
{
    const int blk = blockIdx.x;
    const int b = blk >> 4, ch = blk & 15;
    const int t0 = ch * 32;
    const int tid = threadIdx.x;
    const int dir = tid >> 7, col = tid & 127;

    __shared__ __align__(16) float4 xs[32 * 4];   // x[b][t0..t0+31][0..15]
    if (tid < 128) xs[tid] = ((const float4*)(x + ((size_t)b * SEQ + t0) * DIN))[tid];

    const float* W = dir ? Wb : Wf;
    float w[DIN];
#pragma unroll
    for (int d = 0; d < DIN; ++d) w[d] = W[d * G4 + col];
    const float bias = (dir ? bb : bf)[col];
    __syncthreads();

    float* dst = xw + (((size_t)b * 2 + dir) * SEQ + t0) * G4 + col;
    for (int tl = 0; tl < 32; ++tl) {
        const float4 xa = xs[tl * 4 + 0], xb = xs[tl * 4 + 1];
        const float4 xc = xs[tl * 4 + 2], xd = xs[tl * 4 + 3];
        float a0 = bias, a1 = 0.f, a2 = 0.f, a3 = 0.f;
        a0 = fmaf(xa.x, w[0], a0);  a0 = fmaf(xa.y, w[1], a0);
        a0 = fmaf(xa.z, w[2], a0);  a0 = fmaf(xa.w, w[3], a0);
        a1 = fmaf(xb.x, w[4], a1);  a1 = fmaf(xb.y, w[5], a1);
        a1 = fmaf(xb.z, w[6], a1);  a1 = fmaf(xb.w, w[7], a1);
        a2 = fmaf(xc.x, w[8], a2);  a2 = fmaf(xc.y, w[9], a2);
        a2 = fmaf(xc.z, w[10], a2); a2 = fmaf(xc.w, w[11], a2);
        a3 = fmaf(xd.x, w[12], a3); a3 = fmaf(xd.y, w[13], a3);
        a3 = fmaf(xd.z, w[14], a3); a3 = fmaf(xd.w, w[15], a3);
        dst[(size_t)tl * G4] = (a0 + a1) + (a2 + a3);
    }
}

// ---------------- Kernel 1: BiLSTM scan (1 wave per (b,dir), 1 exchange/step) ---
// Lanes 0..31 compute (i,g) gates; lanes 32..63 compute (f,o).
// c/h STATE LIVES ON HI LANES: lo sends si*tg up via one shfl_xor(32);
// hi does c = sf*c + si*tg, h = so*tanh(c). h broadcast via readlane(32+k).
__global__ __launch_bounds__(64) void lstm_xw_kernel(
    const float* __restrict__ xw,
    const float* __restrict__ Uf, const float* __restrict__ Ub,
    float* __restrict__ hbuf)
{
    const int b = blockIdx.x >> 1;
    const int dir = blockIdx.x & 1;
    const int t0 = threadIdx.x;
    const int c0 = t0, c1 = t0 + 64;

    const float* U = dir ? Ub : Uf;
    float u0[HID], u1[HID];
#pragma unroll
    for (int k = 0; k < HID; ++k) { u0[k] = U[k * G4 + c0]; u1[k] = U[k * G4 + c1]; }

    const bool lo = (t0 < 32);
    // branchless gate-1 params: lo -> tanh(g), hi -> sigmoid(o)
    const float s1  = lo ? (2.0f * LOG2E) : -LOG2E;
    const float a1c = lo ? -2.0f : 1.0f;
    const float b1c = lo ? 1.0f : 0.0f;

    const float* xwp = xw + ((size_t)b * 2 + dir) * SEQ * G4;
    float* outp = hbuf + (size_t)b * SEQ * DH + dir * HID + (t0 & 31);

    // tx(t) = dir ? SEQ-1-t : t ; depth-2 prefetch of the xw stream
    float cur0 = xwp[(size_t)(dir ? SEQ - 1 : 0) * G4 + c0];
    float cur1 = xwp[(size_t)(dir ? SEQ - 1 : 0) * G4 + c1];
    float nx0  = xwp[(size_t)(dir ? SEQ - 2 : 1) * G4 + c0];
    float nx1  = xwp[(size_t)(dir ? SEQ - 2 : 1) * G4 + c1];

    float c = 0.f, hv = 0.f;

    for (int t = 0; t < SEQ; ++t) {
        const int tcur = dir ? (SEQ - 1 - t) : t;
        const int tpre = (t + 2 < SEQ) ? (dir ? (SEQ - 3 - t) : (t + 2)) : tcur;
        const float f0 = xwp[(size_t)tpre * G4 + c0];
        const float f1 = xwp[(size_t)tpre * G4 + c1];

        // z = xw_t + U^T h : 4 independent chains per column
        float q00 = 0.f, q01 = 0.f, q02 = 0.f, q03 = 0.f;
        float q10 = 0.f, q11 = 0.f, q12 = 0.f, q13 = 0.f;
#pragma unroll
        for (int k = 0; k < 16; k += 2) {
            const float h0 = rlane(hv, 32 + k);
            const float h1 = rlane(hv, 32 + k + 1);
            q02 = fmaf(h0, u0[k], q02);      q12 = fmaf(h0, u1[k], q12);
            q03 = fmaf(h1, u0[k + 1], q03);  q13 = fmaf(h1, u1[k + 1], q13);
        }
#pragma unroll
        for (int k = 16; k < 32; k += 2) {
            const float h0 = rlane(hv, 32 + k);
            const float h1 = rlane(hv, 32 + k + 1);
            q00 = fmaf(h0, u0[k], q00);      q10 = fmaf(h0, u1[k], q10);
            q01 = fmaf(h1, u0[k + 1], q01);  q11 = fmaf(h1, u1[k + 1], q11);
        }
        const float z0 = ((q00 + q01) + (q02 + q03)) + cur0;
        const float z1 = ((q10 + q11) + (q12 + q13)) + cur1;

        const float g0 = rcpf(1.0f + exp2f(z0 * -LOG2E));   // si | sf
        const float e1 = exp2f(z1 * s1);
        const float g1 = fmaf(a1c, rcpf(1.0f + e1), b1c);   // tg | so
        const float p  = g0 * g1;                           // lo: si*tg
        const float q  = __shfl_xor(p, 32);                 // hi receives si*tg
        c = fmaf(g0, c, q);                                 // hi: sf*c + si*tg
        hv = g1 * tanh_fast(c);                             // hi: so*tanh(c)
        if (!lo) outp[(size_t)tcur * DH] = hv;

        cur0 = nx0; cur1 = nx1; nx0 = f0; nx1 = f1;
    }
}

// ---------------- Kernel 2: flash attention, RB=64, fused pooled ----------------
// grid: BATCH*8, block 256. Thread: 4 rows (rgrp*4+i) x 4 keys (sgrp+16u).
// att is never materialized: pooled[b][d] += sum_rows h[r][d]*att[r][d] via atomics.
#define RB 64
#define CK 64
#define PS 68   // 68%32=4 -> <=2-way bank aliasing on all access patterns

__global__ __launch_bounds__(256) void attn_kernel(
    const float* __restrict__ h, float* __restrict__ pooled)
{
    const int b   = blockIdx.x >> 3;
    const int rb  = blockIdx.x & 7;
    const int tid = threadIdx.x;
    const int row0 = rb * RB;
    const int rgrp = tid >> 4;          // 0..15
    const int sgrp = tid & 15;          // 0..15

    __shared__ __align__(16) float qL[RB][PS];   // 17.4 KB
    __shared__ __align__(16) float kv[CK][PS];   // 17.4 KB
    __shared__ __align__(16) float pL[RB][PS];   // 17.4 KB

    const float* hb = h + (size_t)b * SEQ * DH;

    for (int i = tid; i < RB * 16; i += 256) {
        const int r = i >> 4, dq = i & 15;
        *(float4*)&qL[r][dq * 4] = *(const float4*)&hb[(row0 + r) * DH + dq * 4];
    }

    float m[4], l[4], o[4][4];
#pragma unroll
    for (int i = 0; i < 4; ++i) {
        m[i] = -1e30f; l[i] = 0.f;
#pragma unroll
        for (int j = 0; j < 4; ++j) o[i][j] = 0.f;
    }
    __syncthreads();

    for (int cc = 0; cc < SEQ / CK; ++cc) {
        const float* src = hb + (size_t)(cc * CK) * DH;
        for (int i = tid; i < CK * 16; i += 256) {
            const int r = i >> 4, dq = i & 15;
            *(float4*)&kv[r][dq * 4] = *(const float4*)&src[r * DH + dq * 4];
        }
        __syncthreads();

        // QK^T: 4x4 register tile
        float a[4][4];
#pragma unroll
        for (int i = 0; i < 4; ++i)
#pragma unroll
            for (int u = 0; u < 4; ++u) a[i][u] = 0.f;

#pragma unroll 2
        for (int d0 = 0; d0 < 16; ++d0) {
            float4 q4[4], k4[4];
#pragma unroll
            for (int i = 0; i < 4; ++i) q4[i] = *(const float4*)&qL[rgrp * 4 + i][d0 * 4];
#pragma unroll
            for (int u = 0; u < 4; ++u) k4[u] = *(const float4*)&kv[sgrp + 16 * u][d0 * 4];
#pragma unroll
            for (int i = 0; i < 4; ++i)
#pragma unroll
                for (int u = 0; u < 4; ++u)
                    a[i][u] = fmaf(q4[i].x, k4[u].x, fmaf(q4[i].y, k4[u].y,
                              fmaf(q4[i].z, k4[u].z, fmaf(q4[i].w, k4[u].w, a[i][u]))));
        }

        // online softmax (log2 domain), per row i; state replicated over 16 sgrp lanes
#pragma unroll
        for (int i = 0; i < 4; ++i) {
#pragma unroll
            for (int u = 0; u < 4; ++u) a[i][u] *= LOG2E;
            float cm = fmaxf(fmaxf(a[i][0], a[i][1]), fmaxf(a[i][2], a[i][3]));
#pragma unroll
            for (int msk = 1; msk < 16; msk <<= 1) cm = fmaxf(cm, __shfl_xor(cm, msk));
            const float mn = fmaxf(m[i], cm);
            const float sc = exp2f(m[i] - mn);
            float p[4], ps = 0.f;
#pragma unroll
            for (int u = 0; u < 4; ++u) { p[u] = exp2f(a[i][u] - mn); ps += p[u]; }
#pragma unroll
            for (int msk = 1; msk < 16; msk <<= 1) ps += __shfl_xor(ps, msk);
            l[i] = l[i] * sc + ps; m[i] = mn;
#pragma unroll
            for (int j = 0; j < 4; ++j) o[i][j] *= sc;
#pragma unroll
            for (int u = 0; u < 4; ++u) pL[rgrp * 4 + i][sgrp + 16 * u] = p[u];
        }
        __syncthreads();

        // PV: 4 rows x 4 d-elems, keys in quads
#pragma unroll 2
        for (int sq = 0; sq < 16; ++sq) {
            float4 p4[4], v4[4];
#pragma unroll
            for (int i = 0; i < 4; ++i) p4[i] = *(const float4*)&pL[rgrp * 4 + i][sq * 4];
#pragma unroll
            for (int su = 0; su < 4; ++su) v4[su] = *(const float4*)&kv[sq * 4 + su][sgrp * 4];
#pragma unroll
            for (int i = 0; i < 4; ++i) {
                const float pv[4] = {p4[i].x, p4[i].y, p4[i].z, p4[i].w};
#pragma unroll
                for (int su = 0; su < 4; ++su) {
                    o[i][0] = fmaf(pv[su], v4[su].x, o[i][0]);
                    o[i][1] = fmaf(pv[su], v4[su].y, o[i][1]);
                    o[i][2] = fmaf(pv[su], v4[su].z, o[i][2]);
                    o[i][3] = fmaf(pv[su], v4[su].w, o[i][3]);
                }
            }
        }
        __syncthreads();
    }

    // fused pooled: pd[j] = sum_i h[r_i][d]*att[r_i][d], d = sgrp*4+j
    float pd[4] = {0.f, 0.f, 0.f, 0.f};
#pragma unroll
    for (int i = 0; i < 4; ++i) {
        const float il = rcpf(l[i]);
        const float4 hq = *(const float4*)&qL[rgrp * 4 + i][sgrp * 4];
        pd[0] = fmaf(hq.x, o[i][0] * il, pd[0]);
        pd[1] = fmaf(hq.y, o[i][1] * il, pd[1]);
        pd[2] = fmaf(hq.z, o[i][2] * il, pd[2]);
        pd[3] = fmaf(hq.w, o[i][3] * il, pd[3]);
    }
#pragma unroll
    for (int j = 0; j < 4; ++j) {
        pd[j] += __shfl_xor(pd[j], 16);   // sum the wave's 4 rgrp groups
        pd[j] += __shfl_xor(pd[j], 32);
    }
    if ((threadIdx.x & 63) < 16) {        // one copy per wave
        float* dst = pooled + b * DH + sgrp * 4;
        atomicAdd(&dst[0], pd[0]);
        atomicAdd(&dst[1], pd[1]);
        atomicAdd(&dst[2], pd[2]);
        atomicAdd(&dst[3], pd[3]);
    }
}

// ---------------- Kernel 3: LSTM2 + dense (tiny) ----------------
__global__ __launch_bounds__(128) void final_kernel(
    const float* __restrict__ pooled,
    const float* __restrict__ W2, const float* __restrict__ b2,
    const float* __restrict__ Wd1, const float* __restrict__ bd1,
    const float* __restrict__ Wd2, const float* __restrict__ bd2,
    float* __restrict__ out)
{
    const int b = blockIdx.x;
    const int tid = threadIdx.x;
    __shared__ float pl[DH];
    __shared__ float zsh[G4];
    __shared__ float h2[HID];
    __shared__ float a1s[16];

    if (tid < DH) pl[tid] = pooled[b * DH + tid];
    __syncthreads();

    float z = b2[tid];
#pragma unroll 8
    for (int k = 0; k < DH; ++k) z = fmaf(pl[k], W2[k * G4 + tid], z);
    zsh[tid] = z;
    __syncthreads();
    if (tid < HID) {
        const float zi = zsh[tid], zg = zsh[2 * HID + tid], zo = zsh[3 * HID + tid];
        const float cc = sigf(zi) * tanh_fast(zg);
        h2[tid] = sigf(zo) * tanh_fast(cc);
    }
    __syncthreads();
    if (tid < 16) {
        float a = bd1[tid];
        for (int k = 0; k < HID; ++k) a = fmaf(h2[k], Wd1[k * 16 + tid], a);
        a1s[tid] = fmaxf(a, 0.0f);
    }
    __syncthreads();
    if (tid == 0) {
        float y = bd2[0];
        for (int k = 0; k < 16; ++k) y = fmaf(a1s[k], Wd2[k], y);
        out[b] = y;
    }
}

extern "C" void kernel_launch(void* const* d_in, const int* in_sizes, int n_in,
                              void* d_out, int out_size, void* d_ws, size_t ws_size,
                              hipStream_t stream)
{
    (void)in_sizes; (void)n_in; (void)out_size; (void)ws_size;
    const float* x   = (const float*)d_in[0];
    const float* Wf  = (const float*)d_in[1];
    const float* Uf  = (const float*)d_in[2];
    const float* bf  = (const float*)d_in[3];
    const float* Wb  = (const float*)d_in[4];
    const float* Ub  = (const float*)d_in[5];
    const float* bb  = (const float*)d_in[6];
    const float* W2  = (const float*)d_in[7];
    // d_in[8] = U2 unused (zero initial state in second LSTM)
    const float* b2  = (const float*)d_in[9];
    const float* Wd1 = (const float*)d_in[10];
    const float* bd1 = (const float*)d_in[11];
    const float* Wd2 = (const float*)d_in[12];
    const float* bd2 = (const float*)d_in[13];
    float* out = (float*)d_out;

    // ws layout (~84 MB; round-7 run proved ws_size covers this):
    const size_t xw_elems   = (size_t)BATCH * 2 * SEQ * G4;   // 67.1 MB
    const size_t hbuf_elems = (size_t)BATCH * SEQ * DH;       // 16.8 MB
    float* xw     = (float*)d_ws;
    float* hbuf   = xw + xw_elems;
    float* pooled = hbuf + hbuf_elems;                        // 32 KB

    hipMemsetAsync(pooled, 0, (size_t)BATCH * DH * sizeof(float), stream);
    hipLaunchKernelGGL(xw_kernel, dim3(BATCH * 16), dim3(256), 0, stream,
                       x, Wf, bf, Wb, bb, xw);
    hipLaunchKernelGGL(lstm_xw_kernel, dim3(BATCH * 2), dim3(64), 0, stream,
                       xw, Uf, Ub, hbuf);
    hipLaunchKernelGGL(attn_kernel, dim3(BATCH * 8), dim3(256), 0, stream,
                       hbuf, pooled);
    hipLaunchKernelGGL(final_kernel, dim3(BATCH), dim3(128), 0, stream,
                       pooled, W2, b2, Wd1, bd1, Wd2, bd2, out);
}

// Round 13
// 403.561 us; speedup vs baseline: 1.1141x; 1.1141x over previous
//
#include <hip/hip_runtime.h>
#include <math.h>

#define BATCH 128
#define SEQ 512
#define DIN 16
#define HID 32
#define G4 128   // 4*HID
#define DH 64    // 2*HID
#define LOG2E 1.44269504f

__device__ __forceinline__ float rcpf(float x) { return __builtin_amdgcn_rcpf(x); }
__device__ __forceinline__ float sigf(float x) { return rcpf(1.0f + exp2f(x * -LOG2E)); }
__device__ __forceinline__ float tanh_fast(float x) {
    return 1.0f - 2.0f * rcpf(1.0f + exp2f(x * (2.0f * LOG2E)));
}
__device__ __forceinline__ float rlane(float v, int lane) {
    return __int_as_float(__builtin_amdgcn_readlane(__float_as_int(v), lane));
}

// ---------------- Kernel 0: xW precompute ----------------
// xw[b][dir][t][col] = bias[col] + sum_d x[b][t][d] * W[d][col]
__global__ __launch_bounds__(256) void xw_kernel(
    const float* __restrict__ x,
    const float* __restrict__ Wf, const float* __restrict__ bf,
    const float* __restrict__ Wb, const float* __restrict__ bb,
    float* __restrict__ xw)
{
    const int blk = blockIdx.x;
    const int b = blk >> 4, ch = blk & 15;
    const int t0 = ch * 32;
    const int tid = threadIdx.x;
    const int dir = tid >> 7, col = tid & 127;

    __shared__ __align__(16) float4 xs[32 * 4];   // x[b][t0..t0+31][0..15]
    if (tid < 128) xs[tid] = ((const float4*)(x + ((size_t)b * SEQ + t0) * DIN))[tid];

    const float* W = dir ? Wb : Wf;
    float w[DIN];
#pragma unroll
    for (int d = 0; d < DIN; ++d) w[d] = W[d * G4 + col];
    const float bias = (dir ? bb : bf)[col];
    __syncthreads();

    float* dst = xw + (((size_t)b * 2 + dir) * SEQ + t0) * G4 + col;
    for (int tl = 0; tl < 32; ++tl) {
        const float4 xa = xs[tl * 4 + 0], xb = xs[tl * 4 + 1];
        const float4 xc = xs[tl * 4 + 2], xd = xs[tl * 4 + 3];
        float a0 = bias, a1 = 0.f, a2 = 0.f, a3 = 0.f;
        a0 = fmaf(xa.x, w[0], a0);  a0 = fmaf(xa.y, w[1], a0);
        a0 = fmaf(xa.z, w[2], a0);  a0 = fmaf(xa.w, w[3], a0);
        a1 = fmaf(xb.x, w[4], a1);  a1 = fmaf(xb.y, w[5], a1);
        a1 = fmaf(xb.z, w[6], a1);  a1 = fmaf(xb.w, w[7], a1);
        a2 = fmaf(xc.x, w[8], a2);  a2 = fmaf(xc.y, w[9], a2);
        a2 = fmaf(xc.z, w[10], a2); a2 = fmaf(xc.w, w[11], a2);
        a3 = fmaf(xd.x, w[12], a3); a3 = fmaf(xd.y, w[13], a3);
        a3 = fmaf(xd.z, w[14], a3); a3 = fmaf(xd.w, w[15], a3);
        dst[(size_t)tl * G4] = (a0 + a1) + (a2 + a3);
    }
}

// ---------------- Kernel 1: BiLSTM scan, 8-step block register prefetch --------
// 1 wave per (b,dir). Lanes 0..31 compute (i,g); lanes 32..63 compute (f,o).
// c/h state on hi lanes; one shfl_xor(32)/step. xw stream loaded one full
// 8-step block ahead into named registers (static indices -> no scratch):
// slack ~8 steps (>2000 cy) >> worst-case HBM latency (~900 cy).
__global__ __launch_bounds__(64) void lstm_xw_kernel(
    const float* __restrict__ xw,
    const float* __restrict__ Uf, const float* __restrict__ Ub,
    float* __restrict__ hbuf)
{
    const int b = blockIdx.x >> 1;
    const int dir = blockIdx.x & 1;
    const int t0 = threadIdx.x;
    const int c0 = t0, c1 = t0 + 64;

    const float* U = dir ? Ub : Uf;
    float u0[HID], u1[HID];
#pragma unroll
    for (int k = 0; k < HID; ++k) { u0[k] = U[k * G4 + c0]; u1[k] = U[k * G4 + c1]; }

    const bool lo = (t0 < 32);
    // branchless gate-1 params: lo -> tanh(g), hi -> sigmoid(o)
    const float s1  = lo ? (2.0f * LOG2E) : -LOG2E;
    const float a1c = lo ? -2.0f : 1.0f;
    const float b1c = lo ? 1.0f : 0.0f;

    const float* xwp = xw + ((size_t)b * 2 + dir) * SEQ * G4;
    const ptrdiff_t sgn  = dir ? -(ptrdiff_t)G4 : (ptrdiff_t)G4;   // step stride in xw
    const ptrdiff_t osgn = dir ? -(ptrdiff_t)DH : (ptrdiff_t)DH;   // step stride in hbuf
    const float* pcur = xwp + (size_t)(dir ? (SEQ - 1) : 0) * G4;
    float* po = hbuf + (size_t)b * SEQ * DH
              + (size_t)(dir ? (SEQ - 1) : 0) * DH + dir * HID + (t0 & 31);

    float cb0[8], cb1[8], nb0[8], nb1[8];
#pragma unroll
    for (int j = 0; j < 8; ++j) {
        cb0[j] = pcur[j * sgn + c0];
        cb1[j] = pcur[j * sgn + c1];
    }

    float c = 0.f, hv = 0.f;

    for (int blk = 0; blk < SEQ / 8; ++blk) {
        const float* pnext = pcur + 8 * sgn;
        if (blk < SEQ / 8 - 1) {
#pragma unroll
            for (int j = 0; j < 8; ++j) {      // issue next block's 16 loads now;
                nb0[j] = pnext[j * sgn + c0];  // first use is the rotate below,
                nb1[j] = pnext[j * sgn + c1];  // ~8 steps (>2000 cy) later
            }
        }

#pragma unroll
        for (int j = 0; j < 8; ++j) {
            // z = xw_t + U^T h : 4 independent chains per column
            float q00 = 0.f, q01 = 0.f, q02 = 0.f, q03 = 0.f;
            float q10 = 0.f, q11 = 0.f, q12 = 0.f, q13 = 0.f;
#pragma unroll
            for (int k = 0; k < 16; k += 2) {
                const float h0 = rlane(hv, 32 + k);
                const float h1 = rlane(hv, 32 + k + 1);
                q02 = fmaf(h0, u0[k], q02);      q12 = fmaf(h0, u1[k], q12);
                q03 = fmaf(h1, u0[k + 1], q03);  q13 = fmaf(h1, u1[k + 1], q13);
            }
#pragma unroll
            for (int k = 16; k < 32; k += 2) {
                const float h0 = rlane(hv, 32 + k);
                const float h1 = rlane(hv, 32 + k + 1);
                q00 = fmaf(h0, u0[k], q00);      q10 = fmaf(h0, u1[k], q10);
                q01 = fmaf(h1, u0[k + 1], q01);  q11 = fmaf(h1, u1[k + 1], q11);
            }
            const float z0 = ((q00 + q01) + (q02 + q03)) + cb0[j];
            const float z1 = ((q10 + q11) + (q12 + q13)) + cb1[j];

            const float g0 = rcpf(1.0f + exp2f(z0 * -LOG2E));   // si | sf
            const float e1 = exp2f(z1 * s1);
            const float g1 = fmaf(a1c, rcpf(1.0f + e1), b1c);   // tg | so
            const float p  = g0 * g1;                           // lo: si*tg
            const float q  = __shfl_xor(p, 32);                 // hi receives si*tg
            c = fmaf(g0, c, q);                                 // hi: sf*c + si*tg
            hv = g1 * tanh_fast(c);                             // hi: so*tanh(c)
            if (!lo) po[j * osgn] = hv;
        }

#pragma unroll
        for (int j = 0; j < 8; ++j) { cb0[j] = nb0[j]; cb1[j] = nb1[j]; }
        pcur = pnext;
        po += 8 * osgn;
    }
}

// ---------------- Kernel 2: flash attention, RB=64, fused pooled ----------------
// grid: BATCH*8, block 256. Thread: 4 rows (rgrp*4+i) x 4 keys (sgrp+16u).
// att is never materialized: pooled[b][d] += sum_rows h[r][d]*att[r][d] via atomics.
#define RB 64
#define CK 64
#define PS 68   // 68%32=4 -> <=2-way bank aliasing on all access patterns

__global__ __launch_bounds__(256) void attn_kernel(
    const float* __restrict__ h, float* __restrict__ pooled)
{
    const int b   = blockIdx.x >> 3;
    const int rb  = blockIdx.x & 7;
    const int tid = threadIdx.x;
    const int row0 = rb * RB;
    const int rgrp = tid >> 4;          // 0..15
    const int sgrp = tid & 15;          // 0..15

    __shared__ __align__(16) float qL[RB][PS];   // 17.4 KB
    __shared__ __align__(16) float kv[CK][PS];   // 17.4 KB
    __shared__ __align__(16) float pL[RB][PS];   // 17.4 KB

    const float* hb = h + (size_t)b * SEQ * DH;

    for (int i = tid; i < RB * 16; i += 256) {
        const int r = i >> 4, dq = i & 15;
        *(float4*)&qL[r][dq * 4] = *(const float4*)&hb[(row0 + r) * DH + dq * 4];
    }

    float m[4], l[4], o[4][4];
#pragma unroll
    for (int i = 0; i < 4; ++i) {
        m[i] = -1e30f; l[i] = 0.f;
#pragma unroll
        for (int j = 0; j < 4; ++j) o[i][j] = 0.f;
    }
    __syncthreads();

    for (int cc = 0; cc < SEQ / CK; ++cc) {
        const float* src = hb + (size_t)(cc * CK) * DH;
        for (int i = tid; i < CK * 16; i += 256) {
            const int r = i >> 4, dq = i & 15;
            *(float4*)&kv[r][dq * 4] = *(const float4*)&src[r * DH + dq * 4];
        }
        __syncthreads();

        // QK^T: 4x4 register tile
        float a[4][4];
#pragma unroll
        for (int i = 0; i < 4; ++i)
#pragma unroll
            for (int u = 0; u < 4; ++u) a[i][u] = 0.f;

#pragma unroll 2
        for (int d0 = 0; d0 < 16; ++d0) {
            float4 q4[4], k4[4];
#pragma unroll
            for (int i = 0; i < 4; ++i) q4[i] = *(const float4*)&qL[rgrp * 4 + i][d0 * 4];
#pragma unroll
            for (int u = 0; u < 4; ++u) k4[u] = *(const float4*)&kv[sgrp + 16 * u][d0 * 4];
#pragma unroll
            for (int i = 0; i < 4; ++i)
#pragma unroll
                for (int u = 0; u < 4; ++u)
                    a[i][u] = fmaf(q4[i].x, k4[u].x, fmaf(q4[i].y, k4[u].y,
                              fmaf(q4[i].z, k4[u].z, fmaf(q4[i].w, k4[u].w, a[i][u]))));
        }

        // online softmax (log2 domain), per row i; state replicated over 16 sgrp lanes
#pragma unroll
        for (int i = 0; i < 4; ++i) {
#pragma unroll
            for (int u = 0; u < 4; ++u) a[i][u] *= LOG2E;
            float cm = fmaxf(fmaxf(a[i][0], a[i][1]), fmaxf(a[i][2], a[i][3]));
#pragma unroll
            for (int msk = 1; msk < 16; msk <<= 1) cm = fmaxf(cm, __shfl_xor(cm, msk));
            const float mn = fmaxf(m[i], cm);
            const float sc = exp2f(m[i] - mn);
            float p[4], ps = 0.f;
#pragma unroll
            for (int u = 0; u < 4; ++u) { p[u] = exp2f(a[i][u] - mn); ps += p[u]; }
#pragma unroll
            for (int msk = 1; msk < 16; msk <<= 1) ps += __shfl_xor(ps, msk);
            l[i] = l[i] * sc + ps; m[i] = mn;
#pragma unroll
            for (int j = 0; j < 4; ++j) o[i][j] *= sc;
#pragma unroll
            for (int u = 0; u < 4; ++u) pL[rgrp * 4 + i][sgrp + 16 * u] = p[u];
        }
        __syncthreads();

        // PV: 4 rows x 4 d-elems, keys in quads
#pragma unroll 2
        for (int sq = 0; sq < 16; ++sq) {
            float4 p4[4], v4[4];
#pragma unroll
            for (int i = 0; i < 4; ++i) p4[i] = *(const float4*)&pL[rgrp * 4 + i][sq * 4];
#pragma unroll
            for (int su = 0; su < 4; ++su) v4[su] = *(const float4*)&kv[sq * 4 + su][sgrp * 4];
#pragma unroll
            for (int i = 0; i < 4; ++i) {
                const float pv[4] = {p4[i].x, p4[i].y, p4[i].z, p4[i].w};
#pragma unroll
                for (int su = 0; su < 4; ++su) {
                    o[i][0] = fmaf(pv[su], v4[su].x, o[i][0]);
                    o[i][1] = fmaf(pv[su], v4[su].y, o[i][1]);
                    o[i][2] = fmaf(pv[su], v4[su].z, o[i][2]);
                    o[i][3] = fmaf(pv[su], v4[su].w, o[i][3]);
                }
            }
        }
        __syncthreads();
    }

    // fused pooled: pd[j] = sum_i h[r_i][d]*att[r_i][d], d = sgrp*4+j
    float pd[4] = {0.f, 0.f, 0.f, 0.f};
#pragma unroll
    for (int i = 0; i < 4; ++i) {
        const float il = rcpf(l[i]);
        const float4 hq = *(const float4*)&qL[rgrp * 4 + i][sgrp * 4];
        pd[0] = fmaf(hq.x, o[i][0] * il, pd[0]);
        pd[1] = fmaf(hq.y, o[i][1] * il, pd[1]);
        pd[2] = fmaf(hq.z, o[i][2] * il, pd[2]);
        pd[3] = fmaf(hq.w, o[i][3] * il, pd[3]);
    }
#pragma unroll
    for (int j = 0; j < 4; ++j) {
        pd[j] += __shfl_xor(pd[j], 16);   // sum the wave's 4 rgrp groups
        pd[j] += __shfl_xor(pd[j], 32);
    }
    if ((threadIdx.x & 63) < 16) {        // one copy per wave
        float* dst = pooled + b * DH + sgrp * 4;
        atomicAdd(&dst[0], pd[0]);
        atomicAdd(&dst[1], pd[1]);
        atomicAdd(&dst[2], pd[2]);
        atomicAdd(&dst[3], pd[3]);
    }
}

// ---------------- Kernel 3: LSTM2 + dense (tiny) ----------------
__global__ __launch_bounds__(128) void final_kernel(
    const float* __restrict__ pooled,
    const float* __restrict__ W2, const float* __restrict__ b2,
    const float* __restrict__ Wd1, const float* __restrict__ bd1,
    const float* __restrict__ Wd2, const float* __restrict__ bd2,
    float* __restrict__ out)
{
    const int b = blockIdx.x;
    const int tid = threadIdx.x;
    __shared__ float pl[DH];
    __shared__ float zsh[G4];
    __shared__ float h2[HID];
    __shared__ float a1s[16];

    if (tid < DH) pl[tid] = pooled[b * DH + tid];
    __syncthreads();

    float z = b2[tid];
#pragma unroll 8
    for (int k = 0; k < DH; ++k) z = fmaf(pl[k], W2[k * G4 + tid], z);
    zsh[tid] = z;
    __syncthreads();
    if (tid < HID) {
        const float zi = zsh[tid], zg = zsh[2 * HID + tid], zo = zsh[3 * HID + tid];
        const float cc = sigf(zi) * tanh_fast(zg);
        h2[tid] = sigf(zo) * tanh_fast(cc);
    }
    __syncthreads();
    if (tid < 16) {
        float a = bd1[tid];
        for (int k = 0; k < HID; ++k) a = fmaf(h2[k], Wd1[k * 16 + tid], a);
        a1s[tid] = fmaxf(a, 0.0f);
    }
    __syncthreads();
    if (tid == 0) {
        float y = bd2[0];
        for (int k = 0; k < 16; ++k) y = fmaf(a1s[k], Wd2[k], y);
        out[b] = y;
    }
}

extern "C" void kernel_launch(void* const* d_in, const int* in_sizes, int n_in,
                              void* d_out, int out_size, void* d_ws, size_t ws_size,
                              hipStream_t stream)
{
    (void)in_sizes; (void)n_in; (void)out_size; (void)ws_size;
    const float* x   = (const float*)d_in[0];
    const float* Wf  = (const float*)d_in[1];
    const float* Uf  = (const float*)d_in[2];
    const float* bf  = (const float*)d_in[3];
    const float* Wb  = (const float*)d_in[4];
    const float* Ub  = (const float*)d_in[5];
    const float* bb  = (const float*)d_in[6];
    const float* W2  = (const float*)d_in[7];
    // d_in[8] = U2 unused (zero initial state in second LSTM)
    const float* b2  = (const float*)d_in[9];
    const float* Wd1 = (const float*)d_in[10];
    const float* bd1 = (const float*)d_in[11];
    const float* Wd2 = (const float*)d_in[12];
    const float* bd2 = (const float*)d_in[13];
    float* out = (float*)d_out;

    const size_t xw_elems   = (size_t)BATCH * 2 * SEQ * G4;   // 67.1 MB
    const size_t hbuf_elems = (size_t)BATCH * SEQ * DH;       // 16.8 MB
    float* xw     = (float*)d_ws;
    float* hbuf   = xw + xw_elems;
    float* pooled = hbuf + hbuf_elems;                        // 32 KB

    hipMemsetAsync(pooled, 0, (size_t)BATCH * DH * sizeof(float), stream);
    hipLaunchKernelGGL(xw_kernel, dim3(BATCH * 16), dim3(256), 0, stream,
                       x, Wf, bf, Wb, bb, xw);
    hipLaunchKernelGGL(lstm_xw_kernel, dim3(BATCH * 2), dim3(64), 0, stream,
                       xw, Uf, Ub, hbuf);
    hipLaunchKernelGGL(attn_kernel, dim3(BATCH * 8), dim3(256), 0, stream,
                       hbuf, pooled);
    hipLaunchKernelGGL(final_kernel, dim3(BATCH), dim3(128), 0, stream,
                       pooled, W2, b2, Wd1, bd1, Wd2, bd2, out);
}